// Round 1
// baseline (251.245 us; speedup 1.0000x reference)
//
#include <hip/hip_runtime.h>

// GraphConv: out = relu( D * A_hat * D * x * W ),  B=8, N=2048, F=O=128, fp32.
// R6: two kernels.
//  K1 (pre): rowsum d over ALL blocks (24/40 split) + xW (unscaled, bf16) on
//            blocks<256 with per-block LDS W-transpose (XOR-swizzled).
//            d[m] is no longer baked into yt -> xW independent of rowsum.
//  K2 (gemm): out = relu(d[n]*(adj_raw*d[m] @ yt^T + (1-adj[n,n])*d[n]*yt[:,n]))
//            d[m] folded into the A-fragment bf16 convert (fp32 mul, single round).
//            adj re-read should be L3-resident (134 MB < 256 MB) after K1.

typedef __bf16 bf16x8 __attribute__((ext_vector_type(8)));
typedef float  f32x4  __attribute__((ext_vector_type(4)));

#define NN 2048
#define NB 8

__device__ __forceinline__ void load_lds16(__bf16* lds, const __bf16* g) {
    // per-lane global src; LDS dest = wave-uniform base + lane*16
    __builtin_amdgcn_global_load_lds(
        (const __attribute__((address_space(1))) void*)g,
        (__attribute__((address_space(3))) void*)lds, 16, 0, 0);
}

// ---------------- K1: degree rowsum (all blocks) + xW (blocks < 256) ------
__global__ __launch_bounds__(256) void pre_kernel(const float* __restrict__ x,
                                                  const float* __restrict__ adj,
                                                  const float* __restrict__ W,
                                                  float* __restrict__ dvec,
                                                  __bf16* __restrict__ yt) {
    __shared__ __bf16 WtL[128 * 128];   // 32 KB, xW blocks only

    const int bid  = blockIdx.x;
    const int lane = threadIdx.x & 63;
    const int wave = threadIdx.x >> 6;

    // --- rowsum: xW blocks do 24 rows, pure-rowsum blocks do 40 ---
    int rbase, rcnt;
    if (bid < 256) { rbase = bid * 24;                rcnt = 6;  }
    else           { rbase = 6144 + (bid - 256) * 40; rcnt = 10; }

    for (int i = 0; i < rcnt; ++i) {
        const int row = rbase + wave * rcnt + i;
        const float* rp = adj + (size_t)row * NN;
        float4 s4 = {0.f, 0.f, 0.f, 0.f};
#pragma unroll
        for (int it = 0; it < 8; ++it) {
            float4 v = *(const float4*)(rp + it * 256 + lane * 4);
            s4.x += v.x; s4.y += v.y; s4.z += v.z; s4.w += v.w;
        }
        float s = (s4.x + s4.y) + (s4.z + s4.w);
#pragma unroll
        for (int off = 32; off; off >>= 1) s += __shfl_down(s, off);
        if (lane == 0) {
            int n = row & (NN - 1);
            float sh = s - rp[n] + 1.0f;            // zero diag, add self-loop
            dvec[row] = 1.0f / (1e-6f + sqrtf(sh));
        }
    }

    if (bid >= 256) return;

    // --- W -> LDS transpose-convert, XOR-swizzled (2-way = free on read) ---
    {
        const int t  = threadIdx.x;
        const int f  = t >> 1;
        const int o0 = (t & 1) * 64;
        const float* wp = W + f * 128 + o0;
#pragma unroll
        for (int j = 0; j < 64; j += 4) {
            float4 w4 = *(const float4*)(wp + j);
            float wv[4] = {w4.x, w4.y, w4.z, w4.w};
#pragma unroll
            for (int u = 0; u < 4; ++u) {
                int o = o0 + j + u;
                WtL[o * 128 + (f ^ ((o & 7) << 3))] = (__bf16)wv[u];
            }
        }
    }
    __syncthreads();

    // --- xW: wave computes 16 m-rows x 128 o-cols of x@W (UNSCALED) -------
    const int b    = bid & 7;
    const int mt   = (bid >> 3) * 4 + wave;          // 0..127
    const int m0   = mt * 16;
    const int kgrp = (lane >> 4) * 8;
    const float* xp = x + ((size_t)b * NN + m0 + (lane & 15)) * 128 + kgrp;

    f32x4 acc[8];
#pragma unroll
    for (int i = 0; i < 8; ++i) acc[i] = (f32x4){0.f, 0.f, 0.f, 0.f};

#pragma unroll
    for (int kt = 0; kt < 4; ++kt) {
        f32x4 a0 = *(const f32x4*)(xp + kt * 32);
        f32x4 a1 = *(const f32x4*)(xp + kt * 32 + 4);
        float av[8] = {a0.x, a0.y, a0.z, a0.w, a1.x, a1.y, a1.z, a1.w};
        bf16x8 af;
#pragma unroll
        for (int j = 0; j < 8; ++j) af[j] = (__bf16)av[j];
#pragma unroll
        for (int nb = 0; nb < 8; ++nb) {
            int c = nb * 16 + (lane & 15);
            bf16x8 bfv = *(const bf16x8*)(
                &WtL[c * 128 + ((kt * 32 + kgrp) ^ ((c & 7) << 3))]);
            acc[nb] = __builtin_amdgcn_mfma_f32_16x16x32_bf16(af, bfv, acc[nb], 0, 0, 0);
        }
    }
    const int col0 = lane & 15;
    const int rq   = (lane >> 4) * 4;
#pragma unroll
    for (int r = 0; r < 4; ++r) {
        int m = m0 + rq + r;
#pragma unroll
        for (int nb = 0; nb < 8; ++nb) {
            int o = nb * 16 + col0;
            yt[((size_t)b * 128 + o) * NN + m] = (__bf16)acc[nb][r];
        }
    }
}

// ---------------- K2: direct-A GEMM, d[m] folded into A-frag --------------
// Block 256 thr: 32 rows x 128 cols; wave w: rows (w&1)*16, cols (w>>1)*64.
// grid 512 (2 blocks/CU), b = blockIdx.x & 7.
__global__ __launch_bounds__(256) void gemm_kernel(const float* __restrict__ adj,
                                                   const __bf16* __restrict__ yt,
                                                   const float* __restrict__ dvec,
                                                   float* __restrict__ out) {
    __shared__ alignas(16) __bf16 sB[2][128][32];

    const int tid  = threadIdx.x;
    const int wave = tid >> 6;
    const int lane = tid & 63;
    const int b    = blockIdx.x & 7;
    const int tile = blockIdx.x >> 3;            // 0..63
    const int rsel = (wave & 1) * 16;
    const int csel = (wave >> 1) * 64;
    const int kgrp = (lane >> 4) * 8;

    const int arow_loc = tile * 32 + rsel + (lane & 15);
    const float* ap = adj + ((size_t)b * NN + arow_loc) * NN + kgrp;
    const float* dp = dvec + b * NN + kgrp;

    const __bf16* ytb = yt + (size_t)b * 128 * NN;
    const int b_row0 = wave * 32;
    const __bf16* b_src = ytb + (size_t)(b_row0 + (lane >> 2)) * NN + (lane & 3) * 8;

    f32x4 acc[4];
#pragma unroll
    for (int i = 0; i < 4; ++i) acc[i] = (f32x4){0.f, 0.f, 0.f, 0.f};

    // preload iter 0
    load_lds16(&sB[0][b_row0][0], b_src);
    load_lds16(&sB[0][b_row0 + 16][0], b_src + (size_t)16 * NN);
    f32x4 ca0 = *(const f32x4*)(ap);
    f32x4 ca1 = *(const f32x4*)(ap + 4);
    f32x4 cd0 = *(const f32x4*)(dp);
    f32x4 cd1 = *(const f32x4*)(dp + 4);

    for (int kt = 0; kt < 64; ++kt) {
        const int cur = kt & 1;
        __syncthreads();   // drains loads issued last iter (glds + A/d regs)

        f32x4 na0, na1, nd0, nd1;
        if (kt + 1 < 64) {
            const __bf16* bs = b_src + (size_t)(kt + 1) * 32;
            load_lds16(&sB[cur ^ 1][b_row0][0], bs);
            load_lds16(&sB[cur ^ 1][b_row0 + 16][0], bs + (size_t)16 * NN);
            na0 = *(const f32x4*)(ap + (kt + 1) * 32);
            na1 = *(const f32x4*)(ap + (kt + 1) * 32 + 4);
            nd0 = *(const f32x4*)(dp + (kt + 1) * 32);
            nd1 = *(const f32x4*)(dp + (kt + 1) * 32 + 4);
        }

        // A-frag = bf16( adj[n,m] * d[m] ) — fp32 multiply, single rounding
        bf16x8 af;
        af[0] = (__bf16)(ca0.x * cd0.x); af[1] = (__bf16)(ca0.y * cd0.y);
        af[2] = (__bf16)(ca0.z * cd0.z); af[3] = (__bf16)(ca0.w * cd0.w);
        af[4] = (__bf16)(ca1.x * cd1.x); af[5] = (__bf16)(ca1.y * cd1.y);
        af[6] = (__bf16)(ca1.z * cd1.z); af[7] = (__bf16)(ca1.w * cd1.w);

#pragma unroll
        for (int nb = 0; nb < 4; ++nb) {
            bf16x8 bfv = *(const bf16x8*)(
                &sB[cur][csel + nb * 16 + (lane & 15)][kgrp]);
            acc[nb] = __builtin_amdgcn_mfma_f32_16x16x32_bf16(af, bfv, acc[nb], 0, 0, 0);
        }
        ca0 = na0; ca1 = na1; cd0 = nd0; cd1 = nd1;
    }

    // epilogue: out = d[n] * (acc + (1 - adj[n,n]) * d[n] * yt[o][n]), relu
    const int col0 = lane & 15;
    const int rq   = (lane >> 4) * 4;
#pragma unroll
    for (int r = 0; r < 4; ++r) {
        int n_loc = tile * 32 + rsel + rq + r;
        size_t grow = (size_t)b * NN + n_loc;
        float dn   = dvec[grow];
        float cfac = (1.0f - adj[grow * NN + n_loc]) * dn;
#pragma unroll
        for (int nb = 0; nb < 4; ++nb) {
            int o = csel + nb * 16 + col0;
            float yp = (float)ytb[(size_t)o * NN + n_loc];
            float v = (acc[nb][r] + cfac * yp) * dn;
            out[grow * 128 + o] = v > 0.f ? v : 0.f;
        }
    }
}

extern "C" void kernel_launch(void* const* d_in, const int* in_sizes, int n_in,
                              void* d_out, int out_size, void* d_ws, size_t ws_size,
                              hipStream_t stream) {
    const float* x   = (const float*)d_in[0];   // [8,2048,128]
    const float* adj = (const float*)d_in[1];   // [8,2048,2048]
    const float* W   = (const float*)d_in[2];   // [128,128]
    float* out = (float*)d_out;

    char* ws = (char*)d_ws;
    float*  dvec = (float*)ws;                          // 64 KB
    __bf16* yt   = (__bf16*)(ws + (128 << 10));         // 4 MB  [B][128][2048]

    hipLaunchKernelGGL(pre_kernel, dim3(512), dim3(256), 0, stream,
                       x, adj, W, dvec, yt);
    hipLaunchKernelGGL(gemm_kernel, dim3(512), dim3(256), 0, stream,
                       adj, yt, dvec, out);
}